// Round 3
// baseline (124.782 us; speedup 1.0000x reference)
//
#include <hip/hip_runtime.h>

typedef unsigned short u16;
typedef unsigned int u32;

#define BB 8
#define CC 128
#define TT_ 1000
#define TPAD 1024
#define NB 31
#define MAXBW 16
#define MAXOC 128

typedef __bf16 bf16x8 __attribute__((ext_vector_type(8)));
typedef float f32x4 __attribute__((ext_vector_type(4)));

__device__ __forceinline__ u16 f2bf(float f) {
    u32 u = __float_as_uint(f);
    return (u16)((u + 0x7fffu + ((u >> 16) & 1u)) >> 16);
}
__device__ __forceinline__ float bf2f(u16 h) { return __uint_as_float(((u32)h) << 16); }
__device__ __forceinline__ int bandBW(int i) { return (i < 10) ? 3 : ((i < 22) ? 8 : ((i < 30) ? 16 : 3)); }
__device__ __forceinline__ int bandF0(int i) {
    return (i < 10) ? 3 * i : ((i < 22) ? 30 + 8 * (i - 10) : ((i < 30) ? 126 + 16 * (i - 22) : 254));
}
// Per-band channel permutation (K-dim permutation, applied to BOTH xt and wgT2;
// MFMA dot over K is permutation-invariant when both operands agree).
// Chosen so the kstat scatter-write is LDS-bank-conflict-free.
__device__ __forceinline__ int bandSW(int i) { return ((i >> 2) << 3) | ((i & 3) << 1); }

// ==================== FULL PATH ====================

// kstat v8: transpose to xt[band][t(1024 pad)][cpos] bf16, cpos = c ^ sw(band).
// READ MAPPING CHANGE (contiguity probe): c0 = tid>>5, k0 = tid&31 (k0==31 idle).
// Each 32-lane half-wave now reads ONE contiguous aligned 496-B run per
// instruction (previously ~3 segments split at arbitrary lane positions).
// Everything else (LDS swizzle, store pass, stats) identical to v7.
__device__ __forceinline__ void kstat_tail(const u16* tile, u16* __restrict__ xt,
                                           float* __restrict__ partials,
                                           int q, int bl, int b, int tid) {
    const uint4* t4 = (const uint4*)tile;       // chunk index: (band*4+tl)*16 + m
    uint4* dst4 = (uint4*)xt;
    const int t0 = q * 4;
    // store pass: linear copy; per wave-instr one band's 4x256B = 1KB contiguous
    for (int n = tid; n < 1984; n += 256) {     // 124 tasks * 16 chunks
        int task = n >> 4, m = n & 15;
        int band = task >> 2, tl = task & 3;
        uint4 u = t4[task * 16 + m];
        dst4[((size_t)(bl * NB + band) * TPAD + t0 + tl) * 16 + m] = u;
    }
    // stats: 8 lanes/band, register accumulation, shfl reduce (order-invariant)
    if (tid < 248) {
        int band = tid >> 3, slot = tid & 7;
        float s = 0.f, sq = 0.f;
        #pragma unroll
        for (int r = 0; r < 8; ++r) {
            int tl = r >> 1, m = slot + 8 * (r & 1);
            uint4 u = t4[(band * 4 + tl) * 16 + m];
            #pragma unroll
            for (int w = 0; w < 4; ++w) {
                u32 uu = (&u.x)[w];
                float f0 = __uint_as_float(uu << 16);
                float f1 = __uint_as_float(uu & 0xffff0000u);
                s += f0 + f1;
                sq += f0 * f0 + f1 * f1;
            }
        }
        #pragma unroll
        for (int off = 1; off < 8; off <<= 1) {
            s  += __shfl_xor(s, off);
            sq += __shfl_xor(sq, off);
        }
        if (slot == 0) {
            *(float2*)&partials[((size_t)(b * NB + band) * 250 + q) * 2] = make_float2(s, sq);
        }
    }
}

__global__ __launch_bounds__(256, 4) void kstat(const float* __restrict__ x,
                                                u16* __restrict__ xt,
                                                float* __restrict__ partials,
                                                int b0) {
    const int bx = blockIdx.x, bl = blockIdx.y, b = b0 + bl, tid = threadIdx.x;
    __shared__ __align__(16) u16 tile[NB * 512];   // 31,744 B
    const float4* src4 = (const float4*)(x + (size_t)b * (CC * TT_ * NB));

    // thread-constant decomposition: c0 in 0..7 per 32-lane group, k0 = lane in group
    const int c0 = tid >> 5;        // 0..7
    const int k0 = tid & 31;        // 0..31 (31 = idle)
    const bool act = (k0 < 31);
    int rowbase[4], swj[4];
    #pragma unroll
    for (int j = 0; j < 4; ++j) {
        int e = 4 * k0 + j;         // 0..123 = tl*31 + band  (garbage if k0==31, unused)
        int tl = (e >= 93) ? 3 : ((e >= 62) ? 2 : ((e >= 31) ? 1 : 0));
        int band = e - tl * 31;
        rowbase[j] = (band * 4 + tl) * 128;
        swj[j] = bandSW(band & 31);
    }

    const int q0 = bx * 2, q1 = bx * 2 + 1;
    float4 v[16];

    // ---- chunk 0: deep load + consume ----
    if (act) {
        const int base = c0 * 7750 + q0 * 31 + k0;
        #pragma unroll
        for (int s = 0; s < 16; ++s) v[s] = src4[base + s * 62000];
        __builtin_amdgcn_sched_barrier(0);
        #pragma unroll
        for (int s = 0; s < 16; ++s) {
            int c = 8 * s + c0;
            #pragma unroll
            for (int j = 0; j < 4; ++j)
                tile[rowbase[j] + (c ^ swj[j])] = f2bf((&v[s].x)[j]);
        }
    }
    __syncthreads();

    // ---- issue chunk-1 loads, then store/stats chunk 0 (latency hidden) ----
    if (act) {
        const int base = c0 * 7750 + q1 * 31 + k0;
        #pragma unroll
        for (int s = 0; s < 16; ++s) v[s] = src4[base + s * 62000];
        __builtin_amdgcn_sched_barrier(0);
    }
    kstat_tail((const u16*)tile, xt, partials, q0, bl, b, tid);
    __syncthreads();

    // ---- consume chunk 1 ----
    if (act) {
        #pragma unroll
        for (int s = 0; s < 16; ++s) {
            int c = 8 * s + c0;
            #pragma unroll
            for (int j = 0; j < 4; ++j)
                tile[rowbase[j] + (c ^ swj[j])] = f2bf((&v[s].x)[j]);
        }
    }
    __syncthreads();
    kstat_tail((const u16*)tile, xt, partials, q1, bl, b, tid);
}

// kfoldW v3: wb/wgs dot products + bf16 wgT2[band][oc(128)][cpos(128)] with the
// SAME per-band channel permutation cpos = c ^ sw(band) as xt (rows >= oc zeroed).
__global__ __launch_bounds__(128) void kfoldW(const float* __restrict__ w,
                                              const float* __restrict__ gamma,
                                              const float* __restrict__ beta,
                                              u16* __restrict__ wgT2,
                                              float* __restrict__ wbArr,
                                              float* __restrict__ wgsArr) {
    const int i = blockIdx.x, tid = threadIdx.x;
    __shared__ float g[CC], be[CC];
    g[tid] = gamma[i * CC + tid];
    be[tid] = beta[i * CC + tid];
    __syncthreads();
    const int oc = bandBW(i) * 8;
    // part 1: thread = output row o
    float wb = 0.f, wgs = 0.f;
    for (int c = 0; c < CC; ++c) {
        float wv = w[(size_t)(i * MAXOC + tid) * CC + c];
        wb += wv * be[c];
        wgs += wv * g[c];
    }
    wbArr[i * CC + tid] = wb;
    wgsArr[i * CC + tid] = wgs;
    // part 2: thread = column c (coalesced within the 256B row segment)
    const float gc = g[tid];
    const int cp = tid ^ bandSW(i);
    for (int o = 0; o < MAXOC; ++o) {
        float wv = w[(size_t)(i * MAXOC + o) * CC + tid];
        wgT2[(size_t)(i * MAXOC + o) * CC + cp] = (o < oc) ? f2bf(wv * gc) : (u16)0;
    }
}

// kmm v3: MFMA 16x16x32 bf16, with kbias FUSED into the block prologue:
// each block reduces partials[(b,i)][0..250) -> mean/rstd, then builds
// bo[row] = cb + wb - mean*rstd*wgs in LDS. Removes the kbias dispatch and
// the beff/rstdArr round-trip.
// C/D mapping (m89-verified): col = lane&15 (t), row = (lane>>4)*4 + reg (oc).
template <int ROWS, int WM, int WN, int RF, int CF, int TSTEP, int NSTEPS, int BCLASS>
__global__ __launch_bounds__(256) void kmmf(const u16* __restrict__ xt,
                                            const u16* __restrict__ wgT2,
                                            const float* __restrict__ partials,
                                            const float* __restrict__ wbArr,
                                            const float* __restrict__ wgsArr,
                                            const float* __restrict__ cb,
                                            const float* __restrict__ ctxr,
                                            const float* __restrict__ ctxi,
                                            float* __restrict__ out,
                                            int b0, long long outSize) {
    const int bx = blockIdx.x, by = blockIdx.y, bl = blockIdx.z;
    const int b = b0 + bl;
    const int i = (BCLASS == 0) ? (by < 10 ? by : 30) : (BCLASS == 1 ? 10 + by : 22 + by);
    const int tid = threadIdx.x;
    const int w = tid >> 6, l = tid & 63;
    const int wm = w % WM, wn = w / WM;
    const int RB = wm * 16 * RF;          // wave row base
    const int CB = wn * 16 * CF;          // wave col base (within t-step)
    const int lr = l & 15, lk = l >> 4;

    __shared__ float Y[ROWS][TSTEP + 1];
    __shared__ float bo[ROWS];
    __shared__ float red[8];

    // ---- fused stats reduction (was kbias) ----
    float s = 0.f, sq = 0.f;
    for (int n = tid; n < 250; n += 256) {
        float2 p = *(const float2*)&partials[((size_t)(b * NB + i) * 250 + n) * 2];
        s += p.x; sq += p.y;
    }
    #pragma unroll
    for (int off = 1; off < 64; off <<= 1) {
        s  += __shfl_xor(s, off);
        sq += __shfl_xor(sq, off);
    }
    if ((tid & 63) == 0) {
        red[(tid >> 6) * 2]     = s;
        red[(tid >> 6) * 2 + 1] = sq;
    }
    __syncthreads();
    s  = red[0] + red[2] + red[4] + red[6];
    sq = red[1] + red[3] + red[5] + red[7];
    const float mean = s * (1.f / 128000.f);
    const float var  = sq * (1.f / 128000.f) - mean * mean;
    const float rstd = rsqrtf(var + 1e-8f);
    for (int n = tid; n < ROWS; n += 256)
        bo[n] = cb[i * MAXOC + n] + wbArr[i * CC + n] - mean * rstd * wgsArr[i * CC + n];

    // A fragments in registers (persist across t-steps)
    const uint4* wb4 = (const uint4*)(wgT2 + (size_t)i * MAXOC * CC);
    bf16x8 a[RF][4];
    #pragma unroll
    for (int rf = 0; rf < RF; ++rf)
        #pragma unroll
        for (int ks = 0; ks < 4; ++ks)
            a[rf][ks] = __builtin_bit_cast(bf16x8,
                wb4[((RB + rf * 16 + lr) * CC + lk * 8 + ks * 32) >> 3]);

    const uint4* xb4 = (const uint4*)(xt + (size_t)(bl * NB + i) * TPAD * CC);
    const int bw = bandBW(i), F0 = bandF0(i);

    for (int st = 0; st < NSTEPS; ++st) {
        const int t0 = (bx * NSTEPS + st) * TSTEP;
        __syncthreads();   // Y free (prev epilogue done); also covers bo on st=0

        // B fragments (direct from global; L1-resident across waves)
        bf16x8 bf[CF][4];
        #pragma unroll
        for (int cf = 0; cf < CF; ++cf)
            #pragma unroll
            for (int ks = 0; ks < 4; ++ks)
                bf[cf][ks] = __builtin_bit_cast(bf16x8,
                    xb4[((size_t)(t0 + CB + cf * 16 + lr) * CC + lk * 8 + ks * 32) >> 3]);

        f32x4 acc[RF][CF];
        #pragma unroll
        for (int rf = 0; rf < RF; ++rf)
            #pragma unroll
            for (int cf = 0; cf < CF; ++cf)
                acc[rf][cf] = (f32x4){0.f, 0.f, 0.f, 0.f};

        #pragma unroll
        for (int ks = 0; ks < 4; ++ks)
            #pragma unroll
            for (int rf = 0; rf < RF; ++rf)
                #pragma unroll
                for (int cf = 0; cf < CF; ++cf)
                    acc[rf][cf] = __builtin_amdgcn_mfma_f32_16x16x32_bf16(
                        a[rf][ks], bf[cf][ks], acc[rf][cf], 0, 0, 0);

        // scale + bias + relu -> Y
        #pragma unroll
        for (int rf = 0; rf < RF; ++rf)
            #pragma unroll
            for (int cf = 0; cf < CF; ++cf)
                #pragma unroll
                for (int r = 0; r < 4; ++r) {
                    int row = RB + rf * 16 + lk * 4 + r;
                    float v = rstd * acc[rf][cf][r] + bo[row];
                    Y[row][CB + cf * 16 + lr] = fmaxf(v, 0.f);
                }
        __syncthreads();

        // GLU + complex mask; REAL plane only, guarded
        const int jobs = 2 * bw * TSTEP;
        for (int n = tid; n < jobs; n += 256) {
            int tl = n % TSTEP, sf = n / TSTEP;
            int ss = sf / bw, f = sf - ss * bw;
            int t = t0 + tl;
            if (t < TT_) {
                float lrv = Y[ss * bw + f][tl];
                float liv = Y[2 * bw + ss * bw + f][tl];
                float grv = Y[4 * bw + ss * bw + f][tl];
                float giv = Y[6 * bw + ss * bw + f][tl];
                float mr = lrv * (1.f / (1.f + __expf(-grv)));
                float mi = liv * (1.f / (1.f + __expf(-giv)));
                size_t cidx = ((size_t)(i * BB + b) * MAXBW + f) * TT_ + t;
                float cr = ctxr[cidx], ci = ctxi[cidx];
                long long ridx = ((long long)((b * 2 + ss) * 257 + F0 + f)) * TT_ + t;
                if (ridx < outSize) out[ridx] = cr * mr - ci * mi;
            }
        }
    }
}

// ==================== FALLBACK (proven in round 6; zero workspace) ====================
template <int ROWS, int RPT, int BCLASS>
__global__ __launch_bounds__(256) void kreal(const float* __restrict__ x,
                                             const float* __restrict__ ctxr,
                                             const float* __restrict__ ctxi,
                                             const float* __restrict__ gamma,
                                             const float* __restrict__ beta,
                                             const float* __restrict__ w,
                                             const float* __restrict__ cb,
                                             float* __restrict__ out,
                                             long long outSize) {
    constexpr int TCH = 64, TPT = 4;
    const int by = blockIdx.x, b = blockIdx.y;
    const int i = (BCLASS == 0) ? (by < 10 ? by : 30) : (BCLASS == 1 ? 10 + by : 22 + by);
    const int tid = threadIdx.x, tx = tid & 15, ty = tid >> 4;

    __shared__ float XN[CC][TCH];
    __shared__ float WT[16][ROWS];
    __shared__ float gl[CC], bt[CC];
    __shared__ float red[8];

    const float* xb = x + (size_t)b * CC * TT_ * NB + i;

    if (tid < CC) { gl[tid] = gamma[i * CC + tid]; bt[tid] = beta[i * CC + tid]; }

    float s = 0.f, sq = 0.f;
    for (int n = tid; n < CC * TT_; n += 256) {
        float v = xb[(size_t)n * NB];
        s += v; sq += v * v;
    }
    #pragma unroll
    for (int off = 1; off < 64; off <<= 1) {
        s  += __shfl_xor(s, off);
        sq += __shfl_xor(sq, off);
    }
    if ((tid & 63) == 0) { red[(tid >> 6) * 2] = s; red[(tid >> 6) * 2 + 1] = sq; }
    __syncthreads();
    s  = red[0] + red[2] + red[4] + red[6];
    sq = red[1] + red[3] + red[5] + red[7];
    const float mean = s * (1.f / 128000.f);
    const float var  = sq * (1.f / 128000.f) - mean * mean;
    const float rstd = rsqrtf(var + 1e-8f);

    const int bw = bandBW(i), F0 = bandF0(i);
    const float* wband = w + (size_t)i * MAXOC * CC;

    for (int t0 = 0; t0 < TT_; t0 += TCH) {
        __syncthreads();
        for (int n = tid; n < CC * TCH; n += 256) {
            int c = n / TCH, tl = n % TCH;
            int t = t0 + tl;
            float v = (t < TT_) ? xb[((size_t)c * TT_ + t) * NB] : 0.f;
            XN[c][tl] = (v - mean) * rstd * gl[c] + bt[c];
        }

        float acc[RPT][TPT];
        #pragma unroll
        for (int r = 0; r < RPT; ++r)
            #pragma unroll
            for (int q = 0; q < TPT; ++q) acc[r][q] = 0.f;

        for (int k0 = 0; k0 < CC; k0 += 16) {
            for (int n = tid; n < 16 * ROWS; n += 256) {
                int kk = n / ROWS, o = n % ROWS;
                WT[kk][o] = wband[(size_t)o * CC + (k0 + kk)];
            }
            __syncthreads();
            #pragma unroll
            for (int kk = 0; kk < 16; ++kk) {
                float wv[RPT], xv[TPT];
                #pragma unroll
                for (int r = 0; r < RPT; ++r) wv[r] = WT[kk][ty * RPT + r];
                #pragma unroll
                for (int q = 0; q < TPT; ++q) xv[q] = XN[k0 + kk][tx * TPT + q];
                #pragma unroll
                for (int r = 0; r < RPT; ++r)
                    #pragma unroll
                    for (int q = 0; q < TPT; ++q) acc[r][q] = fmaf(wv[r], xv[q], acc[r][q]);
            }
            __syncthreads();
        }

        float* Yb = &XN[0][0];
        #pragma unroll
        for (int r = 0; r < RPT; ++r) {
            int o = ty * RPT + r;
            float bv = cb[i * MAXOC + o];
            #pragma unroll
            for (int q = 0; q < TPT; ++q)
                Yb[o * TCH + tx * TPT + q] = fmaxf(acc[r][q] + bv, 0.f);
        }
        __syncthreads();

        const int jobs = 2 * bw * TCH;
        for (int n = tid; n < jobs; n += 256) {
            int tl = n % TCH, sf = n / TCH;
            int ss = sf / bw, f = sf - ss * bw;
            int t = t0 + tl;
            if (t < TT_) {
                float lrv = Yb[(ss * bw + f) * TCH + tl];
                float liv = Yb[(2 * bw + ss * bw + f) * TCH + tl];
                float grv = Yb[(4 * bw + ss * bw + f) * TCH + tl];
                float giv = Yb[(6 * bw + ss * bw + f) * TCH + tl];
                float mr = lrv * (1.f / (1.f + __expf(-grv)));
                float mi = liv * (1.f / (1.f + __expf(-giv)));
                size_t cidx = ((size_t)(i * BB + b) * MAXBW + f) * TT_ + t;
                float cr = ctxr[cidx], ci = ctxi[cidx];
                long long ridx = ((long long)((b * 2 + ss) * 257 + F0 + f)) * TT_ + t;
                if (ridx < outSize) out[ridx] = cr * mr - ci * mi;
            }
        }
    }
}

extern "C" void kernel_launch(void* const* d_in, const int* in_sizes, int n_in,
                              void* d_out, int out_size, void* d_ws, size_t ws_size,
                              hipStream_t stream) {
    const float* sep   = (const float*)d_in[0];
    const float* ctxr  = (const float*)d_in[2];
    const float* ctxi  = (const float*)d_in[3];
    const float* gamma = (const float*)d_in[4];
    const float* beta  = (const float*)d_in[5];
    const float* convw = (const float*)d_in[6];
    const float* convb = (const float*)d_in[7];
    float* out = (float*)d_out;

    long long outSize = (long long)out_size;   // real plane, strictly guarded

    const size_t fixedEnd = 1671936;
    const size_t perB = (size_t)NB * TPAD * CC * 2;   // 8,126,464 B per batch

    if (ws_size >= fixedEnd + perB) {
        char* ws = (char*)d_ws;
        float* partials = (float*)(ws + 0);          // 8*31*250*2*4 = 496,000 B
        float* wbArr    = (float*)(ws + 497408);
        float* wgsArr   = (float*)(ws + 513280);
        u16*   wgT2     = (u16*)(ws + 656128);       // 31*128*128*2 = 1,015,808 B
        u16*   xt       = (u16*)(ws + 1671936);

        int nbper = (int)((ws_size - fixedEnd) / perB);
        if (nbper > BB) nbper = BB;

        kfoldW<<<dim3(NB), 128, 0, stream>>>(convw, gamma, beta, wgT2, wbArr, wgsArr);

        for (int b0 = 0; b0 < BB; b0 += nbper) {
            int nb = (BB - b0 < nbper) ? (BB - b0) : nbper;
            kstat<<<dim3(125, nb), 256, 0, stream>>>(sep, xt, partials, b0);
            // class A: oc=24 (pad 32), bands {0..9,30}: ROWS=32, WM=2, WN=2, TSTEP=128
            kmmf<32, 2, 2, 1, 4, 128, 2, 0><<<dim3(4, 11, nb), 256, 0, stream>>>(xt, wgT2, partials, wbArr, wgsArr, convb, ctxr, ctxi, out, b0, outSize);
            // class B: oc=64, bands 10..21: ROWS=64, WM=4, WN=1, TSTEP=64
            kmmf<64, 4, 1, 1, 4, 64, 2, 1><<<dim3(8, 12, nb), 256, 0, stream>>>(xt, wgT2, partials, wbArr, wgsArr, convb, ctxr, ctxi, out, b0, outSize);
            // class C: oc=128, bands 22..29: ROWS=128, WM=4, WN=1, RF=2, TSTEP=64
            kmmf<128, 4, 1, 2, 4, 64, 2, 2><<<dim3(8, 8, nb), 256, 0, stream>>>(xt, wgT2, partials, wbArr, wgsArr, convb, ctxr, ctxi, out, b0, outSize);
        }
    } else {
        kreal<32, 2, 0><<<dim3(11, BB), 256, 0, stream>>>(sep, ctxr, ctxi, gamma, beta, convw, convb, out, outSize);
        kreal<64, 4, 1><<<dim3(12, BB), 256, 0, stream>>>(sep, ctxr, ctxi, gamma, beta, convw, convb, out, outSize);
        kreal<128, 8, 2><<<dim3(8, BB), 256, 0, stream>>>(sep, ctxr, ctxi, gamma, beta, convw, convb, out, outSize);
    }
}

// Round 4
// 94.659 us; speedup vs baseline: 1.3182x; 1.3182x over previous
//
#include <hip/hip_runtime.h>

typedef unsigned short u16;
typedef unsigned int u32;

#define BB 8
#define CC 128
#define TT_ 1000
#define TPAD 1024
#define NB 31
#define MAXBW 16
#define MAXOC 128

typedef __bf16 bf16x8 __attribute__((ext_vector_type(8)));
typedef float f32x4 __attribute__((ext_vector_type(4)));

__device__ __forceinline__ u16 f2bf(float f) {
    u32 u = __float_as_uint(f);
    return (u16)((u + 0x7fffu + ((u >> 16) & 1u)) >> 16);
}
__device__ __forceinline__ float bf2f(u16 h) { return __uint_as_float(((u32)h) << 16); }
__device__ __forceinline__ int bandBW(int i) { return (i < 10) ? 3 : ((i < 22) ? 8 : ((i < 30) ? 16 : 3)); }
__device__ __forceinline__ int bandF0(int i) {
    return (i < 10) ? 3 * i : ((i < 22) ? 30 + 8 * (i - 10) : ((i < 30) ? 126 + 16 * (i - 22) : 254));
}

// ==================== FULL PATH ====================

// kstat v9: STREAMING transpose. Block = (t-window of 16, c-group of 32, b).
// Reads: 32 runs x 1,984B contiguous; per wave-instruction 64 lanes x float4 =
// 1KB contiguous, instructions walk each run sequentially (m13-copy pattern).
// LDS tile [c-local 32][f 500] u16 (f = tl*31+band): each lane's float4 ->
// ONE ds_write_b64 at lane-linear addresses (conflict-free).
// xt layout: [bl][band][cblk 16][t 1024][8c] bf16 -> store runs of 256B,
// and kmmf B-fragments become 4x256B contiguous per instruction.
// Stats per band from LDS (order-invariant), chunk = tw*4+cg (252 chunks).
__global__ __launch_bounds__(256, 4) void kstat(const float* __restrict__ x,
                                                u16* __restrict__ xt,
                                                float* __restrict__ partials,
                                                int b0) {
    const int tw = blockIdx.x, cg = blockIdx.y, bl = blockIdx.z, b = b0 + bl;
    const int tid = threadIdx.x, lane = tid & 63, w = tid >> 6;
    __shared__ __align__(16) u16 tile[32 * 500];   // 32,000 B
    const int NF4 = (tw == 62) ? 62 : 124;         // float4 per run (16t*31band/4)

    if (tw == 62) {                                // zero-fill pad region (stats/store read it)
        u32* t32 = (u32*)tile;
        for (int n = tid; n < 8000; n += 256) t32[n] = 0;
        __syncthreads();
    }

    const float4* src4 = (const float4*)(x + (size_t)b * (CC * TT_ * NB));
    const int fbase = tw * 124;

    // ---- load phase: 16 float4 per thread, all issued before any use ----
    float4 v[16];
    #pragma unroll
    for (int k = 0; k < 8; ++k) {
        const int c = cg * 32 + w * 8 + k;
        const float4* p = src4 + (size_t)c * 7750 + fbase;
        int o0 = lane;
        int o1 = 64 + lane;
        o0 = (o0 < NF4) ? o0 : 0;                  // clamp (only trims tw==62)
        o1 = (o1 < NF4) ? o1 : 0;
        v[k * 2]     = p[o0];
        v[k * 2 + 1] = p[o1];
    }
    __builtin_amdgcn_sched_barrier(0);

    // ---- convert + LDS write: one b64 per float4, lane-linear ----
    #pragma unroll
    for (int k = 0; k < 8; ++k) {
        const int r = w * 8 + k;
        u16* row = tile + r * 500;
        #pragma unroll
        for (int it = 0; it < 2; ++it) {
            const int off = it * 64 + lane;
            float4 vv = v[k * 2 + it];
            ushort4 pk;
            pk.x = f2bf(vv.x); pk.y = f2bf(vv.y); pk.z = f2bf(vv.z); pk.w = f2bf(vv.w);
            if (off < NF4) *(ushort4*)(row + 4 * off) = pk;
        }
    }
    __syncthreads();

    // ---- store pass: gather 8 c's per uint4, write 256B runs ----
    uint4* dst4 = (uint4*)xt;
    const int t0 = tw * 16;
    for (int n = tid; n < 1984; n += 256) {        // 124 tasks * 16 t
        int task = n >> 4, m = n & 15;             // m = tl
        int band = task >> 2, cbl = task & 3;
        int fidx = m * 31 + band;
        u16 e[8];
        #pragma unroll
        for (int j = 0; j < 8; ++j)
            e[j] = tile[(8 * cbl + j) * 500 + fidx];
        uint4 u;
        u.x = (u32)e[0] | ((u32)e[1] << 16);
        u.y = (u32)e[2] | ((u32)e[3] << 16);
        u.z = (u32)e[4] | ((u32)e[5] << 16);
        u.w = (u32)e[6] | ((u32)e[7] << 16);
        dst4[((size_t)(bl * NB + band) * 16 + (cg * 4 + cbl)) * TPAD + t0 + m] = u;
    }

    // ---- stats: 8 lanes/band (slot covers 2 t's x all 32 c), shfl reduce ----
    if (tid < 248) {
        int band = tid >> 3, slot = tid & 7;
        float s = 0.f, sq = 0.f;
        #pragma unroll
        for (int ci = 0; ci < 32; ++ci) {
            #pragma unroll
            for (int d = 0; d < 2; ++d) {
                float f = bf2f(tile[ci * 500 + (2 * slot + d) * 31 + band]);
                s += f; sq += f * f;
            }
        }
        #pragma unroll
        for (int off = 1; off < 8; off <<= 1) {
            s  += __shfl_xor(s, off);
            sq += __shfl_xor(sq, off);
        }
        if (slot == 0) {
            int ch = tw * 4 + cg;
            *(float2*)&partials[((size_t)(b * NB + band) * 256 + ch) * 2] = make_float2(s, sq);
        }
    }
}

// kfoldW v4: wb/wgs dot products + bf16 wgT2[band][oc(128)][c(128)] (plain c
// order; rows >= oc zeroed).
__global__ __launch_bounds__(128) void kfoldW(const float* __restrict__ w,
                                              const float* __restrict__ gamma,
                                              const float* __restrict__ beta,
                                              u16* __restrict__ wgT2,
                                              float* __restrict__ wbArr,
                                              float* __restrict__ wgsArr) {
    const int i = blockIdx.x, tid = threadIdx.x;
    __shared__ float g[CC], be[CC];
    g[tid] = gamma[i * CC + tid];
    be[tid] = beta[i * CC + tid];
    __syncthreads();
    const int oc = bandBW(i) * 8;
    // part 1: thread = output row o
    float wb = 0.f, wgs = 0.f;
    for (int c = 0; c < CC; ++c) {
        float wv = w[(size_t)(i * MAXOC + tid) * CC + c];
        wb += wv * be[c];
        wgs += wv * g[c];
    }
    wbArr[i * CC + tid] = wb;
    wgsArr[i * CC + tid] = wgs;
    // part 2: thread = column c (coalesced read & write)
    const float gc = g[tid];
    for (int o = 0; o < MAXOC; ++o) {
        float wv = w[(size_t)(i * MAXOC + o) * CC + tid];
        wgT2[(size_t)(i * MAXOC + o) * CC + tid] = (o < oc) ? f2bf(wv * gc) : (u16)0;
    }
}

// kmm v4: MFMA 16x16x32 bf16, kbias fused in prologue; xt blocked-c layout:
// B-fragment (t, c = lk*8+ks*32) -> cblk = lk+4*ks, uint4 at
// ((band*16 + cblk)*TPAD + t) -> per instruction 4 runs of 256B contiguous.
// C/D mapping (m89-verified): col = lane&15 (t), row = (lane>>4)*4 + reg (oc).
template <int ROWS, int WM, int WN, int RF, int CF, int TSTEP, int NSTEPS, int BCLASS>
__global__ __launch_bounds__(256) void kmmf(const u16* __restrict__ xt,
                                            const u16* __restrict__ wgT2,
                                            const float* __restrict__ partials,
                                            const float* __restrict__ wbArr,
                                            const float* __restrict__ wgsArr,
                                            const float* __restrict__ cb,
                                            const float* __restrict__ ctxr,
                                            const float* __restrict__ ctxi,
                                            float* __restrict__ out,
                                            int b0, long long outSize) {
    const int bx = blockIdx.x, by = blockIdx.y, bl = blockIdx.z;
    const int b = b0 + bl;
    const int i = (BCLASS == 0) ? (by < 10 ? by : 30) : (BCLASS == 1 ? 10 + by : 22 + by);
    const int tid = threadIdx.x;
    const int w = tid >> 6, l = tid & 63;
    const int wm = w % WM, wn = w / WM;
    const int RB = wm * 16 * RF;          // wave row base
    const int CB = wn * 16 * CF;          // wave col base (within t-step)
    const int lr = l & 15, lk = l >> 4;

    __shared__ float Y[ROWS][TSTEP + 1];
    __shared__ float bo[ROWS];
    __shared__ float red[8];

    // ---- fused stats reduction (was kbias) ----
    float s = 0.f, sq = 0.f;
    for (int n = tid; n < 252; n += 256) {
        float2 p = *(const float2*)&partials[((size_t)(b * NB + i) * 256 + n) * 2];
        s += p.x; sq += p.y;
    }
    #pragma unroll
    for (int off = 1; off < 64; off <<= 1) {
        s  += __shfl_xor(s, off);
        sq += __shfl_xor(sq, off);
    }
    if ((tid & 63) == 0) {
        red[(tid >> 6) * 2]     = s;
        red[(tid >> 6) * 2 + 1] = sq;
    }
    __syncthreads();
    s  = red[0] + red[2] + red[4] + red[6];
    sq = red[1] + red[3] + red[5] + red[7];
    const float mean = s * (1.f / 128000.f);
    const float var  = sq * (1.f / 128000.f) - mean * mean;
    const float rstd = rsqrtf(var + 1e-8f);
    for (int n = tid; n < ROWS; n += 256)
        bo[n] = cb[i * MAXOC + n] + wbArr[i * CC + n] - mean * rstd * wgsArr[i * CC + n];

    // A fragments in registers (persist across t-steps)
    const uint4* wb4 = (const uint4*)(wgT2 + (size_t)i * MAXOC * CC);
    bf16x8 a[RF][4];
    #pragma unroll
    for (int rf = 0; rf < RF; ++rf)
        #pragma unroll
        for (int ks = 0; ks < 4; ++ks)
            a[rf][ks] = __builtin_bit_cast(bf16x8,
                wb4[((RB + rf * 16 + lr) * CC + lk * 8 + ks * 32) >> 3]);

    const uint4* xb4 = ((const uint4*)xt) + (size_t)(bl * NB + i) * 16 * TPAD;
    const int bw = bandBW(i), F0 = bandF0(i);

    for (int st = 0; st < NSTEPS; ++st) {
        const int t0 = (bx * NSTEPS + st) * TSTEP;
        __syncthreads();   // Y free (prev epilogue done); also covers bo on st=0

        // B fragments (blocked-c layout: cblk = lk + 4*ks)
        bf16x8 bf[CF][4];
        #pragma unroll
        for (int cf = 0; cf < CF; ++cf)
            #pragma unroll
            for (int ks = 0; ks < 4; ++ks)
                bf[cf][ks] = __builtin_bit_cast(bf16x8,
                    xb4[(size_t)(lk + ks * 4) * TPAD + (t0 + CB + cf * 16 + lr)]);

        f32x4 acc[RF][CF];
        #pragma unroll
        for (int rf = 0; rf < RF; ++rf)
            #pragma unroll
            for (int cf = 0; cf < CF; ++cf)
                acc[rf][cf] = (f32x4){0.f, 0.f, 0.f, 0.f};

        #pragma unroll
        for (int ks = 0; ks < 4; ++ks)
            #pragma unroll
            for (int rf = 0; rf < RF; ++rf)
                #pragma unroll
                for (int cf = 0; cf < CF; ++cf)
                    acc[rf][cf] = __builtin_amdgcn_mfma_f32_16x16x32_bf16(
                        a[rf][ks], bf[cf][ks], acc[rf][cf], 0, 0, 0);

        // scale + bias + relu -> Y
        #pragma unroll
        for (int rf = 0; rf < RF; ++rf)
            #pragma unroll
            for (int cf = 0; cf < CF; ++cf)
                #pragma unroll
                for (int r = 0; r < 4; ++r) {
                    int row = RB + rf * 16 + lk * 4 + r;
                    float vv = rstd * acc[rf][cf][r] + bo[row];
                    Y[row][CB + cf * 16 + lr] = fmaxf(vv, 0.f);
                }
        __syncthreads();

        // GLU + complex mask; REAL plane only, guarded
        const int jobs = 2 * bw * TSTEP;
        for (int n = tid; n < jobs; n += 256) {
            int tl = n % TSTEP, sf = n / TSTEP;
            int ss = sf / bw, f = sf - ss * bw;
            int t = t0 + tl;
            if (t < TT_) {
                float lrv = Y[ss * bw + f][tl];
                float liv = Y[2 * bw + ss * bw + f][tl];
                float grv = Y[4 * bw + ss * bw + f][tl];
                float giv = Y[6 * bw + ss * bw + f][tl];
                float mr = lrv * (1.f / (1.f + __expf(-grv)));
                float mi = liv * (1.f / (1.f + __expf(-giv)));
                size_t cidx = ((size_t)(i * BB + b) * MAXBW + f) * TT_ + t;
                float cr = ctxr[cidx], ci = ctxi[cidx];
                long long ridx = ((long long)((b * 2 + ss) * 257 + F0 + f)) * TT_ + t;
                if (ridx < outSize) out[ridx] = cr * mr - ci * mi;
            }
        }
    }
}

// ==================== FALLBACK (proven in round 6; zero workspace) ====================
template <int ROWS, int RPT, int BCLASS>
__global__ __launch_bounds__(256) void kreal(const float* __restrict__ x,
                                             const float* __restrict__ ctxr,
                                             const float* __restrict__ ctxi,
                                             const float* __restrict__ gamma,
                                             const float* __restrict__ beta,
                                             const float* __restrict__ w,
                                             const float* __restrict__ cb,
                                             float* __restrict__ out,
                                             long long outSize) {
    constexpr int TCH = 64, TPT = 4;
    const int by = blockIdx.x, b = blockIdx.y;
    const int i = (BCLASS == 0) ? (by < 10 ? by : 30) : (BCLASS == 1 ? 10 + by : 22 + by);
    const int tid = threadIdx.x, tx = tid & 15, ty = tid >> 4;

    __shared__ float XN[CC][TCH];
    __shared__ float WT[16][ROWS];
    __shared__ float gl[CC], bt[CC];
    __shared__ float red[8];

    const float* xb = x + (size_t)b * CC * TT_ * NB + i;

    if (tid < CC) { gl[tid] = gamma[i * CC + tid]; bt[tid] = beta[i * CC + tid]; }

    float s = 0.f, sq = 0.f;
    for (int n = tid; n < CC * TT_; n += 256) {
        float v = xb[(size_t)n * NB];
        s += v; sq += v * v;
    }
    #pragma unroll
    for (int off = 1; off < 64; off <<= 1) {
        s  += __shfl_xor(s, off);
        sq += __shfl_xor(sq, off);
    }
    if ((tid & 63) == 0) { red[(tid >> 6) * 2] = s; red[(tid >> 6) * 2 + 1] = sq; }
    __syncthreads();
    s  = red[0] + red[2] + red[4] + red[6];
    sq = red[1] + red[3] + red[5] + red[7];
    const float mean = s * (1.f / 128000.f);
    const float var  = sq * (1.f / 128000.f) - mean * mean;
    const float rstd = rsqrtf(var + 1e-8f);

    const int bw = bandBW(i), F0 = bandF0(i);
    const float* wband = w + (size_t)i * MAXOC * CC;

    for (int t0 = 0; t0 < TT_; t0 += TCH) {
        __syncthreads();
        for (int n = tid; n < CC * TCH; n += 256) {
            int c = n / TCH, tl = n % TCH;
            int t = t0 + tl;
            float v = (t < TT_) ? xb[((size_t)c * TT_ + t) * NB] : 0.f;
            XN[c][tl] = (v - mean) * rstd * gl[c] + bt[c];
        }

        float acc[RPT][TPT];
        #pragma unroll
        for (int r = 0; r < RPT; ++r)
            #pragma unroll
            for (int q = 0; q < TPT; ++q) acc[r][q] = 0.f;

        for (int k0 = 0; k0 < CC; k0 += 16) {
            for (int n = tid; n < 16 * ROWS; n += 256) {
                int kk = n / ROWS, o = n % ROWS;
                WT[kk][o] = wband[(size_t)o * CC + (k0 + kk)];
            }
            __syncthreads();
            #pragma unroll
            for (int kk = 0; kk < 16; ++kk) {
                float wv[RPT], xv[TPT];
                #pragma unroll
                for (int r = 0; r < RPT; ++r) wv[r] = WT[kk][ty * RPT + r];
                #pragma unroll
                for (int q = 0; q < TPT; ++q) xv[q] = XN[k0 + kk][tx * TPT + q];
                #pragma unroll
                for (int r = 0; r < RPT; ++r)
                    #pragma unroll
                    for (int q = 0; q < TPT; ++q) acc[r][q] = fmaf(wv[r], xv[q], acc[r][q]);
            }
            __syncthreads();
        }

        float* Yb = &XN[0][0];
        #pragma unroll
        for (int r = 0; r < RPT; ++r) {
            int o = ty * RPT + r;
            float bv = cb[i * MAXOC + o];
            #pragma unroll
            for (int q = 0; q < TPT; ++q)
                Yb[o * TCH + tx * TPT + q] = fmaxf(acc[r][q] + bv, 0.f);
        }
        __syncthreads();

        const int jobs = 2 * bw * TCH;
        for (int n = tid; n < jobs; n += 256) {
            int tl = n % TCH, sf = n / TCH;
            int ss = sf / bw, f = sf - ss * bw;
            int t = t0 + tl;
            if (t < TT_) {
                float lrv = Yb[(ss * bw + f) * TCH + tl];
                float liv = Yb[(2 * bw + ss * bw + f) * TCH + tl];
                float grv = Yb[(4 * bw + ss * bw + f) * TCH + tl];
                float giv = Yb[(6 * bw + ss * bw + f) * TCH + tl];
                float mr = lrv * (1.f / (1.f + __expf(-grv)));
                float mi = liv * (1.f / (1.f + __expf(-giv)));
                size_t cidx = ((size_t)(i * BB + b) * MAXBW + f) * TT_ + t;
                float cr = ctxr[cidx], ci = ctxi[cidx];
                long long ridx = ((long long)((b * 2 + ss) * 257 + F0 + f)) * TT_ + t;
                if (ridx < outSize) out[ridx] = cr * mr - ci * mi;
            }
        }
    }
}

extern "C" void kernel_launch(void* const* d_in, const int* in_sizes, int n_in,
                              void* d_out, int out_size, void* d_ws, size_t ws_size,
                              hipStream_t stream) {
    const float* sep   = (const float*)d_in[0];
    const float* ctxr  = (const float*)d_in[2];
    const float* ctxi  = (const float*)d_in[3];
    const float* gamma = (const float*)d_in[4];
    const float* beta  = (const float*)d_in[5];
    const float* convw = (const float*)d_in[6];
    const float* convb = (const float*)d_in[7];
    float* out = (float*)d_out;

    long long outSize = (long long)out_size;   // real plane, strictly guarded

    const size_t fixedEnd = 1555456;
    const size_t perB = (size_t)NB * 16 * TPAD * 16;  // 8,126,464 B per batch

    if (ws_size >= fixedEnd + perB) {
        char* ws = (char*)d_ws;
        float* partials = (float*)(ws + 0);          // 8*31*256*2*4 = 507,904 B
        float* wbArr    = (float*)(ws + 507904);     // 15,872 B
        float* wgsArr   = (float*)(ws + 523776);     // 15,872 B
        u16*   wgT2     = (u16*)(ws + 539648);       // 31*128*128*2 = 1,015,808 B
        u16*   xt       = (u16*)(ws + 1555456);

        int nbper = (int)((ws_size - fixedEnd) / perB);
        if (nbper > BB) nbper = BB;

        kfoldW<<<dim3(NB), 128, 0, stream>>>(convw, gamma, beta, wgT2, wbArr, wgsArr);

        for (int b0 = 0; b0 < BB; b0 += nbper) {
            int nb = (BB - b0 < nbper) ? (BB - b0) : nbper;
            kstat<<<dim3(63, 4, nb), 256, 0, stream>>>(sep, xt, partials, b0);
            // class A: oc=24 (pad 32), bands {0..9,30}: ROWS=32, WM=2, WN=2, TSTEP=128
            kmmf<32, 2, 2, 1, 4, 128, 2, 0><<<dim3(4, 11, nb), 256, 0, stream>>>(xt, wgT2, partials, wbArr, wgsArr, convb, ctxr, ctxi, out, b0, outSize);
            // class B: oc=64, bands 10..21: ROWS=64, WM=4, WN=1, TSTEP=64
            kmmf<64, 4, 1, 1, 4, 64, 2, 1><<<dim3(8, 12, nb), 256, 0, stream>>>(xt, wgT2, partials, wbArr, wgsArr, convb, ctxr, ctxi, out, b0, outSize);
            // class C: oc=128, bands 22..29: ROWS=128, WM=4, WN=1, RF=2, TSTEP=64
            kmmf<128, 4, 1, 2, 4, 64, 2, 2><<<dim3(8, 8, nb), 256, 0, stream>>>(xt, wgT2, partials, wbArr, wgsArr, convb, ctxr, ctxi, out, b0, outSize);
        }
    } else {
        kreal<32, 2, 0><<<dim3(11, BB), 256, 0, stream>>>(sep, ctxr, ctxi, gamma, beta, convw, convb, out, outSize);
        kreal<64, 4, 1><<<dim3(12, BB), 256, 0, stream>>>(sep, ctxr, ctxi, gamma, beta, convw, convb, out, outSize);
        kreal<128, 8, 2><<<dim3(8, BB), 256, 0, stream>>>(sep, ctxr, ctxi, gamma, beta, convw, convb, out, outSize);
    }
}

// Round 5
// 86.525 us; speedup vs baseline: 1.4422x; 1.0940x over previous
//
#include <hip/hip_runtime.h>

typedef unsigned short u16;
typedef unsigned int u32;

#define BB 8
#define CC 128
#define TT_ 1000
#define TPAD 1024
#define NB 31
#define MAXBW 16
#define MAXOC 128

typedef __bf16 bf16x8 __attribute__((ext_vector_type(8)));
typedef float f32x4 __attribute__((ext_vector_type(4)));

__device__ __forceinline__ u16 f2bf(float f) {
    u32 u = __float_as_uint(f);
    return (u16)((u + 0x7fffu + ((u >> 16) & 1u)) >> 16);
}
__device__ __forceinline__ float bf2f(u16 h) { return __uint_as_float(((u32)h) << 16); }
__device__ __forceinline__ int bandBW(int i) { return (i < 10) ? 3 : ((i < 22) ? 8 : ((i < 30) ? 16 : 3)); }
__device__ __forceinline__ int bandF0(int i) {
    return (i < 10) ? 3 * i : ((i < 22) ? 30 + 8 * (i - 10) : ((i < 30) ? 126 + 16 * (i - 22) : 254));
}

// ==================== FULL PATH ====================

// kstat v10: streaming transpose (proven r4) + kfoldW folded in as tw==63.
// tw<63: Block = (t-window 16, c-group 32, b). 1KB-contiguous read streams,
// lane-linear LDS, xt layout [bl][band][cblk 16][t 1024][8c] bf16.
// tw==63: 4*nb blocks compute wgT2 (bf16 W*gamma), wb/wgs dots per band.
__global__ __launch_bounds__(256, 4) void kstat(const float* __restrict__ x,
                                                const float* __restrict__ convw,
                                                const float* __restrict__ gamma,
                                                const float* __restrict__ beta,
                                                u16* __restrict__ xt,
                                                float* __restrict__ partials,
                                                u16* __restrict__ wgT2,
                                                float* __restrict__ wbArr,
                                                float* __restrict__ wgsArr,
                                                int b0) {
    const int tw = blockIdx.x, cg = blockIdx.y, bl = blockIdx.z, b = b0 + bl;
    const int tid = threadIdx.x, lane = tid & 63, w = tid >> 6;
    __shared__ __align__(16) u16 tile[32 * 500];   // 32,000 B

    if (tw == 63) {
        // ---- fold-W service blocks (was kfoldW) ----
        float* g  = (float*)tile;        // 128 floats
        float* be = g + 128;
        const int nbT = (int)gridDim.z;
        for (int band = cg * nbT + bl; band < NB; band += 4 * nbT) {
            __syncthreads();
            if (tid < 128) { g[tid] = gamma[band * CC + tid]; be[tid] = beta[band * CC + tid]; }
            __syncthreads();
            const int oc = bandBW(band) * 8;
            if (tid < 128) {
                float wb = 0.f, wgs = 0.f;
                for (int c = 0; c < CC; ++c) {
                    float wv = convw[(size_t)(band * MAXOC + tid) * CC + c];
                    wb += wv * be[c];
                    wgs += wv * g[c];
                }
                wbArr[band * CC + tid] = wb;
                wgsArr[band * CC + tid] = wgs;
            }
            const int c = tid & 127, oh = tid >> 7;
            const float gc = g[c];
            for (int o = oh * 64; o < oh * 64 + 64; ++o) {
                float wv = convw[(size_t)(band * MAXOC + o) * CC + c];
                wgT2[(size_t)(band * MAXOC + o) * CC + c] = (o < oc) ? f2bf(wv * gc) : (u16)0;
            }
        }
        return;
    }

    const int NF4 = (tw == 62) ? 62 : 124;         // float4 per run (16t*31band/4)

    if (tw == 62) {                                // zero-fill pad region
        u32* t32 = (u32*)tile;
        for (int n = tid; n < 8000; n += 256) t32[n] = 0;
        __syncthreads();
    }

    const float4* src4 = (const float4*)(x + (size_t)b * (CC * TT_ * NB));
    const int fbase = tw * 124;

    // ---- load phase: 16 float4 per thread, all issued before any use ----
    float4 v[16];
    #pragma unroll
    for (int k = 0; k < 8; ++k) {
        const int c = cg * 32 + w * 8 + k;
        const float4* p = src4 + (size_t)c * 7750 + fbase;
        int o0 = lane;
        int o1 = 64 + lane;
        o0 = (o0 < NF4) ? o0 : 0;
        o1 = (o1 < NF4) ? o1 : 0;
        v[k * 2]     = p[o0];
        v[k * 2 + 1] = p[o1];
    }
    __builtin_amdgcn_sched_barrier(0);

    // ---- convert + LDS write: one b64 per float4, lane-linear ----
    #pragma unroll
    for (int k = 0; k < 8; ++k) {
        const int r = w * 8 + k;
        u16* row = tile + r * 500;
        #pragma unroll
        for (int it = 0; it < 2; ++it) {
            const int off = it * 64 + lane;
            float4 vv = v[k * 2 + it];
            ushort4 pk;
            pk.x = f2bf(vv.x); pk.y = f2bf(vv.y); pk.z = f2bf(vv.z); pk.w = f2bf(vv.w);
            if (off < NF4) *(ushort4*)(row + 4 * off) = pk;
        }
    }
    __syncthreads();

    // ---- store pass: gather 8 c's per uint4, write 256B runs ----
    uint4* dst4 = (uint4*)xt;
    const int t0 = tw * 16;
    for (int n = tid; n < 1984; n += 256) {        // 124 tasks * 16 t
        int task = n >> 4, m = n & 15;             // m = tl
        int band = task >> 2, cbl = task & 3;
        int fidx = m * 31 + band;
        u16 e[8];
        #pragma unroll
        for (int j = 0; j < 8; ++j)
            e[j] = tile[(8 * cbl + j) * 500 + fidx];
        uint4 u;
        u.x = (u32)e[0] | ((u32)e[1] << 16);
        u.y = (u32)e[2] | ((u32)e[3] << 16);
        u.z = (u32)e[4] | ((u32)e[5] << 16);
        u.w = (u32)e[6] | ((u32)e[7] << 16);
        dst4[((size_t)(bl * NB + band) * 16 + (cg * 4 + cbl)) * TPAD + t0 + m] = u;
    }

    // ---- stats: 8 lanes/band, shfl reduce ----
    if (tid < 248) {
        int band = tid >> 3, slot = tid & 7;
        float s = 0.f, sq = 0.f;
        #pragma unroll
        for (int ci = 0; ci < 32; ++ci) {
            #pragma unroll
            for (int d = 0; d < 2; ++d) {
                float f = bf2f(tile[ci * 500 + (2 * slot + d) * 31 + band]);
                s += f; sq += f * f;
            }
        }
        #pragma unroll
        for (int off = 1; off < 8; off <<= 1) {
            s  += __shfl_xor(s, off);
            sq += __shfl_xor(sq, off);
        }
        if (slot == 0) {
            int ch = tw * 4 + cg;
            *(float2*)&partials[((size_t)(b * NB + band) * 256 + ch) * 2] = make_float2(s, sq);
        }
    }
}

// kmm v5: unified single-launch MFMA kernel. by = band (0..30); class chosen by
// block-uniform branch. Y union in dynamic LDS (max 128*33 floats -> 17.4KB).
// B-fragment from xt blocked-c layout: cblk = lk + 4*ks, 4x256B runs/instr.
// C/D mapping (m89-verified): col = lane&15 (t), row = (lane>>4)*4 + reg (oc).
#define YMAXF 4224
template <int ROWS, int WM, int WN, int RF, int CF, int TSTEP, int NSTEPS>
__device__ __forceinline__ void kmm_body(float* __restrict__ Y, float* __restrict__ bo,
                                         float* __restrict__ red,
                                         const u16* __restrict__ xt,
                                         const u16* __restrict__ wgT2,
                                         const float* __restrict__ partials,
                                         const float* __restrict__ wbArr,
                                         const float* __restrict__ wgsArr,
                                         const float* __restrict__ cb,
                                         const float* __restrict__ ctxr,
                                         const float* __restrict__ ctxi,
                                         float* __restrict__ out,
                                         int i, int b, int bl, int bx, long long outSize) {
    const int tid = threadIdx.x;
    const int w = tid >> 6, l = tid & 63;
    const int wm = w % WM, wn = w / WM;
    const int RB = wm * 16 * RF;
    const int CB = wn * 16 * CF;
    const int lr = l & 15, lk = l >> 4;
    constexpr int PITCH = TSTEP + 1;

    // ---- fused stats reduction ----
    float s = 0.f, sq = 0.f;
    for (int n = tid; n < 252; n += 256) {
        float2 p = *(const float2*)&partials[((size_t)(b * NB + i) * 256 + n) * 2];
        s += p.x; sq += p.y;
    }
    #pragma unroll
    for (int off = 1; off < 64; off <<= 1) {
        s  += __shfl_xor(s, off);
        sq += __shfl_xor(sq, off);
    }
    if ((tid & 63) == 0) {
        red[(tid >> 6) * 2]     = s;
        red[(tid >> 6) * 2 + 1] = sq;
    }
    __syncthreads();
    s  = red[0] + red[2] + red[4] + red[6];
    sq = red[1] + red[3] + red[5] + red[7];
    const float mean = s * (1.f / 128000.f);
    const float var  = sq * (1.f / 128000.f) - mean * mean;
    const float rstd = rsqrtf(var + 1e-8f);
    for (int n = tid; n < ROWS; n += 256)
        bo[n] = cb[i * MAXOC + n] + wbArr[i * CC + n] - mean * rstd * wgsArr[i * CC + n];

    // A fragments in registers (persist across t-steps)
    const uint4* wb4 = (const uint4*)(wgT2 + (size_t)i * MAXOC * CC);
    bf16x8 a[RF][4];
    #pragma unroll
    for (int rf = 0; rf < RF; ++rf)
        #pragma unroll
        for (int ks = 0; ks < 4; ++ks)
            a[rf][ks] = __builtin_bit_cast(bf16x8,
                wb4[((RB + rf * 16 + lr) * CC + lk * 8 + ks * 32) >> 3]);

    const uint4* xb4 = ((const uint4*)xt) + (size_t)(bl * NB + i) * 16 * TPAD;
    const int bw = bandBW(i), F0 = bandF0(i);

    for (int st = 0; st < NSTEPS; ++st) {
        const int t0 = (bx * NSTEPS + st) * TSTEP;
        __syncthreads();   // Y free (prev epilogue done); also covers bo on st=0

        // B fragments (blocked-c layout: cblk = lk + 4*ks)
        bf16x8 bf[CF][4];
        #pragma unroll
        for (int cf = 0; cf < CF; ++cf)
            #pragma unroll
            for (int ks = 0; ks < 4; ++ks)
                bf[cf][ks] = __builtin_bit_cast(bf16x8,
                    xb4[(size_t)(lk + ks * 4) * TPAD + (t0 + CB + cf * 16 + lr)]);

        f32x4 acc[RF][CF];
        #pragma unroll
        for (int rf = 0; rf < RF; ++rf)
            #pragma unroll
            for (int cf = 0; cf < CF; ++cf)
                acc[rf][cf] = (f32x4){0.f, 0.f, 0.f, 0.f};

        #pragma unroll
        for (int ks = 0; ks < 4; ++ks)
            #pragma unroll
            for (int rf = 0; rf < RF; ++rf)
                #pragma unroll
                for (int cf = 0; cf < CF; ++cf)
                    acc[rf][cf] = __builtin_amdgcn_mfma_f32_16x16x32_bf16(
                        a[rf][ks], bf[cf][ks], acc[rf][cf], 0, 0, 0);

        // scale + bias + relu -> Y
        #pragma unroll
        for (int rf = 0; rf < RF; ++rf)
            #pragma unroll
            for (int cf = 0; cf < CF; ++cf)
                #pragma unroll
                for (int r = 0; r < 4; ++r) {
                    int row = RB + rf * 16 + lk * 4 + r;
                    float vv = rstd * acc[rf][cf][r] + bo[row];
                    Y[row * PITCH + CB + cf * 16 + lr] = fmaxf(vv, 0.f);
                }
        __syncthreads();

        // GLU + complex mask; REAL plane only, guarded
        const int jobs = 2 * bw * TSTEP;
        for (int n = tid; n < jobs; n += 256) {
            int tl = n % TSTEP, sf = n / TSTEP;
            int ss = sf / bw, f = sf - ss * bw;
            int t = t0 + tl;
            if (t < TT_) {
                float lrv = Y[(ss * bw + f) * PITCH + tl];
                float liv = Y[(2 * bw + ss * bw + f) * PITCH + tl];
                float grv = Y[(4 * bw + ss * bw + f) * PITCH + tl];
                float giv = Y[(6 * bw + ss * bw + f) * PITCH + tl];
                float mr = lrv * (1.f / (1.f + __expf(-grv)));
                float mi = liv * (1.f / (1.f + __expf(-giv)));
                size_t cidx = ((size_t)(i * BB + b) * MAXBW + f) * TT_ + t;
                float cr = ctxr[cidx], ci = ctxi[cidx];
                long long ridx = ((long long)((b * 2 + ss) * 257 + F0 + f)) * TT_ + t;
                if (ridx < outSize) out[ridx] = cr * mr - ci * mi;
            }
        }
    }
}

__global__ __launch_bounds__(256) void kmm(const u16* __restrict__ xt,
                                           const u16* __restrict__ wgT2,
                                           const float* __restrict__ partials,
                                           const float* __restrict__ wbArr,
                                           const float* __restrict__ wgsArr,
                                           const float* __restrict__ cb,
                                           const float* __restrict__ ctxr,
                                           const float* __restrict__ ctxi,
                                           float* __restrict__ out,
                                           int b0, long long outSize) {
    extern __shared__ float smem[];
    float* Y  = smem;
    float* bo = smem + YMAXF;
    float* red = bo + 128;
    const int bx = blockIdx.x, i = blockIdx.y, bl = blockIdx.z, b = b0 + bl;
    if (i < 10 || i == 30)
        kmm_body<32, 2, 2, 1, 4, 128, 1>(Y, bo, red, xt, wgT2, partials, wbArr, wgsArr, cb, ctxr, ctxi, out, i, b, bl, bx, outSize);
    else if (i < 22)
        kmm_body<64, 4, 1, 1, 4, 64, 2>(Y, bo, red, xt, wgT2, partials, wbArr, wgsArr, cb, ctxr, ctxi, out, i, b, bl, bx, outSize);
    else
        kmm_body<128, 4, 1, 2, 2, 32, 4>(Y, bo, red, xt, wgT2, partials, wbArr, wgsArr, cb, ctxr, ctxi, out, i, b, bl, bx, outSize);
}

// ==================== FALLBACK (proven in round 6; zero workspace) ====================
template <int ROWS, int RPT, int BCLASS>
__global__ __launch_bounds__(256) void kreal(const float* __restrict__ x,
                                             const float* __restrict__ ctxr,
                                             const float* __restrict__ ctxi,
                                             const float* __restrict__ gamma,
                                             const float* __restrict__ beta,
                                             const float* __restrict__ w,
                                             const float* __restrict__ cb,
                                             float* __restrict__ out,
                                             long long outSize) {
    constexpr int TCH = 64, TPT = 4;
    const int by = blockIdx.x, b = blockIdx.y;
    const int i = (BCLASS == 0) ? (by < 10 ? by : 30) : (BCLASS == 1 ? 10 + by : 22 + by);
    const int tid = threadIdx.x, tx = tid & 15, ty = tid >> 4;

    __shared__ float XN[CC][TCH];
    __shared__ float WT[16][ROWS];
    __shared__ float gl[CC], bt[CC];
    __shared__ float red[8];

    const float* xb = x + (size_t)b * CC * TT_ * NB + i;

    if (tid < CC) { gl[tid] = gamma[i * CC + tid]; bt[tid] = beta[i * CC + tid]; }

    float s = 0.f, sq = 0.f;
    for (int n = tid; n < CC * TT_; n += 256) {
        float v = xb[(size_t)n * NB];
        s += v; sq += v * v;
    }
    #pragma unroll
    for (int off = 1; off < 64; off <<= 1) {
        s  += __shfl_xor(s, off);
        sq += __shfl_xor(sq, off);
    }
    if ((tid & 63) == 0) { red[(tid >> 6) * 2] = s; red[(tid >> 6) * 2 + 1] = sq; }
    __syncthreads();
    s  = red[0] + red[2] + red[4] + red[6];
    sq = red[1] + red[3] + red[5] + red[7];
    const float mean = s * (1.f / 128000.f);
    const float var  = sq * (1.f / 128000.f) - mean * mean;
    const float rstd = rsqrtf(var + 1e-8f);

    const int bw = bandBW(i), F0 = bandF0(i);
    const float* wband = w + (size_t)i * MAXOC * CC;

    for (int t0 = 0; t0 < TT_; t0 += TCH) {
        __syncthreads();
        for (int n = tid; n < CC * TCH; n += 256) {
            int c = n / TCH, tl = n % TCH;
            int t = t0 + tl;
            float v = (t < TT_) ? xb[((size_t)c * TT_ + t) * NB] : 0.f;
            XN[c][tl] = (v - mean) * rstd * gl[c] + bt[c];
        }

        float acc[RPT][TPT];
        #pragma unroll
        for (int r = 0; r < RPT; ++r)
            #pragma unroll
            for (int q = 0; q < TPT; ++q) acc[r][q] = 0.f;

        for (int k0 = 0; k0 < CC; k0 += 16) {
            for (int n = tid; n < 16 * ROWS; n += 256) {
                int kk = n / ROWS, o = n % ROWS;
                WT[kk][o] = wband[(size_t)o * CC + (k0 + kk)];
            }
            __syncthreads();
            #pragma unroll
            for (int kk = 0; kk < 16; ++kk) {
                float wv[RPT], xv[TPT];
                #pragma unroll
                for (int r = 0; r < RPT; ++r) wv[r] = WT[kk][ty * RPT + r];
                #pragma unroll
                for (int q = 0; q < TPT; ++q) xv[q] = XN[k0 + kk][tx * TPT + q];
                #pragma unroll
                for (int r = 0; r < RPT; ++r)
                    #pragma unroll
                    for (int q = 0; q < TPT; ++q) acc[r][q] = fmaf(wv[r], xv[q], acc[r][q]);
            }
            __syncthreads();
        }

        float* Yb = &XN[0][0];
        #pragma unroll
        for (int r = 0; r < RPT; ++r) {
            int o = ty * RPT + r;
            float bv = cb[i * MAXOC + o];
            #pragma unroll
            for (int q = 0; q < TPT; ++q)
                Yb[o * TCH + tx * TPT + q] = fmaxf(acc[r][q] + bv, 0.f);
        }
        __syncthreads();

        const int jobs = 2 * bw * TCH;
        for (int n = tid; n < jobs; n += 256) {
            int tl = n % TCH, sf = n / TCH;
            int ss = sf / bw, f = sf - ss * bw;
            int t = t0 + tl;
            if (t < TT_) {
                float lrv = Yb[(ss * bw + f) * TCH + tl];
                float liv = Yb[(2 * bw + ss * bw + f) * TCH + tl];
                float grv = Yb[(4 * bw + ss * bw + f) * TCH + tl];
                float giv = Yb[(6 * bw + ss * bw + f) * TCH + tl];
                float mr = lrv * (1.f / (1.f + __expf(-grv)));
                float mi = liv * (1.f / (1.f + __expf(-giv)));
                size_t cidx = ((size_t)(i * BB + b) * MAXBW + f) * TT_ + t;
                float cr = ctxr[cidx], ci = ctxi[cidx];
                long long ridx = ((long long)((b * 2 + ss) * 257 + F0 + f)) * TT_ + t;
                if (ridx < outSize) out[ridx] = cr * mr - ci * mi;
            }
        }
    }
}

extern "C" void kernel_launch(void* const* d_in, const int* in_sizes, int n_in,
                              void* d_out, int out_size, void* d_ws, size_t ws_size,
                              hipStream_t stream) {
    const float* sep   = (const float*)d_in[0];
    const float* ctxr  = (const float*)d_in[2];
    const float* ctxi  = (const float*)d_in[3];
    const float* gamma = (const float*)d_in[4];
    const float* beta  = (const float*)d_in[5];
    const float* convw = (const float*)d_in[6];
    const float* convb = (const float*)d_in[7];
    float* out = (float*)d_out;

    long long outSize = (long long)out_size;   // real plane, strictly guarded

    const size_t fixedEnd = 1555456;
    const size_t perB = (size_t)NB * 16 * TPAD * 16;  // 8,126,464 B per batch

    if (ws_size >= fixedEnd + perB) {
        char* ws = (char*)d_ws;
        float* partials = (float*)(ws + 0);          // 8*31*256*2*4 = 507,904 B
        float* wbArr    = (float*)(ws + 507904);     // 15,872 B
        float* wgsArr   = (float*)(ws + 523776);     // 15,872 B
        u16*   wgT2     = (u16*)(ws + 539648);       // 31*128*128*2 = 1,015,808 B
        u16*   xt       = (u16*)(ws + 1555456);

        int nbper = (int)((ws_size - fixedEnd) / perB);
        if (nbper > BB) nbper = BB;

        const size_t smemB = (size_t)(YMAXF + 128 + 8) * 4;   // 17,440 B

        for (int b0 = 0; b0 < BB; b0 += nbper) {
            int nb = (BB - b0 < nbper) ? (BB - b0) : nbper;
            kstat<<<dim3(64, 4, nb), 256, 0, stream>>>(sep, convw, gamma, beta, xt, partials, wgT2, wbArr, wgsArr, b0);
            kmm<<<dim3(8, NB, nb), 256, smemB, stream>>>(xt, wgT2, partials, wbArr, wgsArr, convb, ctxr, ctxi, out, b0, outSize);
        }
    } else {
        kreal<32, 2, 0><<<dim3(11, BB), 256, 0, stream>>>(sep, ctxr, ctxi, gamma, beta, convw, convb, out, outSize);
        kreal<64, 4, 1><<<dim3(12, BB), 256, 0, stream>>>(sep, ctxr, ctxi, gamma, beta, convw, convb, out, outSize);
        kreal<128, 8, 2><<<dim3(8, BB), 256, 0, stream>>>(sep, ctxr, ctxi, gamma, beta, convw, convb, out, outSize);
    }
}